// Round 9
// baseline (342.340 us; speedup 1.0000x reference)
//
#include <hip/hip_runtime.h>
#include <stdint.h>

// Problem constants
#define F_     128
#define N_     12288
#define NH_    9
#define NSLOT_ 8
#define NVARS_ 8
#define NUP_   (4*N_)
#define K6_    (NH_*F_)   // 1152

typedef __attribute__((ext_vector_type(8))) short bf16x8;
typedef __attribute__((ext_vector_type(4))) float f32x4;

typedef const __attribute__((address_space(1))) unsigned char* gp1_t;
typedef __attribute__((address_space(3))) unsigned char* lp3_t;

__device__ __forceinline__ void load16(const void* g, void* l) {
  __builtin_amdgcn_global_load_lds((gp1_t)g, (lp3_t)l, 16, 0, 0);
}

__device__ __forceinline__ unsigned short f2bf(float f) {
  union { float f; unsigned int u; } x; x.f = f;
  unsigned int u = x.u;
  unsigned int r = u + 0x7FFFu + ((u >> 16) & 1u);   // RNE
  return (unsigned short)(r >> 16);
}

// ---------------- converts ----------------
__global__ void k_conv_emb(const float4* __restrict__ src, ushort4* __restrict__ dst, int n4) {
  int i = blockIdx.x * blockDim.x + threadIdx.x;
  if (i >= n4) return;
  float4 v = src[i];
  ushort4 o;
  o.x = f2bf(v.x); o.y = f2bf(v.y); o.z = f2bf(v.z); o.w = f2bf(v.w);
  dst[i] = o;
}

// LDS-tiled coalesced transpose: dst[c][r] = bf16(src[r][c]); rows,cols multiples of 32.
__global__ __launch_bounds__(256) void k_transpose_bf(
    const float* __restrict__ src, unsigned short* __restrict__ dst, int rows, int cols) {
  __shared__ float tile[32][33];
  const int tx = threadIdx.x & 31, ty = threadIdx.x >> 5;   // 32 x 8
  const int c = blockIdx.x * 32 + tx;
#pragma unroll
  for (int i = 0; i < 4; ++i) {
    const int r = blockIdx.y * 32 + ty + i * 8;
    tile[ty + i * 8][tx] = src[(size_t)r * cols + c];
  }
  __syncthreads();
  const int rr = blockIdx.y * 32 + tx;                      // contiguous in dst row
#pragma unroll
  for (int i = 0; i < 4; ++i) {
    const int cc = blockIdx.x * 32 + ty + i * 8;            // dst row = src col
    dst[(size_t)cc * rows + rr] = f2bf(tile[tx][ty + i * 8]);
  }
}

// ---------------- fused h5+h6: var-dedup GEMM + plane epilogue ----------------
// grid (96, 5, 8): cz 0..3 = h6 child ct (128 rows x 256 cols, 18 K-steps);
//                  cz == 4 = h5 duty     (128 rows x 256 cols,  2 K-steps).
// 512 thr = 8 waves (2 wr x 4 wc). Proven r8 structure: 2-barrier K-loop,
// global_load_lds w16, XOR-swizzled LDS, padded-plane float4 epilogue.
__global__ __launch_bounds__(512) void k_fused(
    const unsigned short* __restrict__ embB,   // [NVARS][N][F] bf16
    const unsigned short* __restrict__ W5T,    // [256][128]  bf16
    const unsigned short* __restrict__ W6T,    // [1024][1152] bf16
    const float* __restrict__ b5,              // [256]
    const float* __restrict__ b6,              // [1024]
    const float* __restrict__ x5,              // [NSLOT][N][F]
    const float* __restrict__ x6,              // [NSLOT][NUP][F]
    const int* __restrict__ var_idx,
    const int* __restrict__ adjc,              // [N][9]
    float* __restrict__ y5,                    // [NSLOT][N][F]
    float* __restrict__ y6)                    // [NSLOT][NUP][F]
{
  const int slot = blockIdx.z;
  const int var = var_idx[slot];
  for (int j = 0; j < NSLOT_; ++j) {
    if (j >= slot) break;
    if (var_idx[j] == var) return;            // uniform per block, before any barrier
  }
  unsigned int fmask = 0;
  for (int j = slot; j < NSLOT_; ++j)
    if (var_idx[j] == var) fmask |= 1u << j;

  // union: GEMM layout (16K A + 32K B + 4.6K ald) vs epilogue planes (2 x 64 x 132 f32)
  __shared__ __align__(1024) unsigned char smem[2 * 64 * 132 * 4];
  unsigned char* Asm = smem;                  // 128 rows x 128 B (swizzled)
  unsigned char* Bsm = smem + 16384;          // 256 rows x 128 B (swizzled)
  int* ald = (int*)(smem + 16384 + 32768);    // 128 x 9 neighbor ids

  const int tid = threadIdx.x;
  const int l = tid & 63, w = tid >> 6;       // 8 waves
  const int wr = w >> 2, wc = w & 3;          // 2 x 4
  const int li8 = l >> 3, pc = l & 7, l15 = l & 15, l16 = l >> 4;

  const int nt = blockIdx.x;                  // 0..95
  const int cz = blockIdx.y;                  // 0..3 = h6 child; 4 = h5
  const int n0 = nt * 128;

  for (int t = tid; t < 128 * NH_; t += 512) ald[t] = adjc[n0 * NH_ + t];
  __syncthreads();

  const f32x4 fz = {0.f, 0.f, 0.f, 0.f};
  f32x4 accS[4][2], accH[4][2];
#pragma unroll
  for (int mf = 0; mf < 4; ++mf)
#pragma unroll
    for (int nf = 0; nf < 2; ++nf) { accS[mf][nf] = fz; accH[mf][nf] = fz; }

  const size_t embVarOff = (size_t)var * ((size_t)N_ * F_);
  float* SP = (float*)smem;                  // [64][132] epilogue planes
  float* HP = SP + 64 * 132;

  if (cz == 4) {
    // =========================== h5 duty ===========================
    for (int step = 0; step < 2; ++step) {
      const int k0 = step << 6;
      // stage A: gathered self rows (h=0)
#pragma unroll
      for (int q2 = 0; q2 < 2; ++q2) {
        const int q = w * 2 + q2;
        const int r = q * 8 + li8;
        const int lc = pc ^ (r & 7);
        const int m = ald[r * NH_];
        const unsigned short* g = embB + embVarOff + (size_t)m * F_ + k0 + lc * 8;
        load16(g, Asm + q * 1024);
      }
      // stage B: W5T rows 0..255, K=128
#pragma unroll
      for (int q2 = 0; q2 < 4; ++q2) {
        const int q = w * 4 + q2;
        const int j = q * 8 + li8;
        const int lc = pc ^ (j & 7);
        const unsigned short* g = W5T + (size_t)j * 128 + k0 + lc * 8;
        load16(g, Bsm + q * 1024);
      }
      __syncthreads();

#pragma unroll
      for (int kf = 0; kf < 2; ++kf) {
        const int kc = kf * 4 + l16;
        bf16x8 a[4], bs[2], bh[2];
#pragma unroll
        for (int mf = 0; mf < 4; ++mf) {
          const int r = wr * 64 + mf * 16 + l15;
          a[mf] = *(const bf16x8*)(Asm + r * 128 + ((kc ^ (r & 7)) << 4));
        }
#pragma unroll
        for (int nf = 0; nf < 2; ++nf) {
          const int js = wc * 32 + nf * 16 + l15;
          bs[nf] = *(const bf16x8*)(Bsm + js * 128 + ((kc ^ (js & 7)) << 4));
          const int jh = js + 128;
          bh[nf] = *(const bf16x8*)(Bsm + jh * 128 + ((kc ^ (jh & 7)) << 4));
        }
#pragma unroll
        for (int mf = 0; mf < 4; ++mf)
#pragma unroll
          for (int nf = 0; nf < 2; ++nf) {
            accS[mf][nf] = __builtin_amdgcn_mfma_f32_16x16x32_bf16(a[mf], bs[nf], accS[mf][nf], 0, 0, 0);
            accH[mf][nf] = __builtin_amdgcn_mfma_f32_16x16x32_bf16(a[mf], bh[nf], accH[mf][nf], 0, 0, 0);
          }
      }
      __syncthreads();
    }

    // plane epilogue -> y5
#pragma unroll 1
    for (int mh = 0; mh < 2; ++mh) {
      if (wr == mh) {
#pragma unroll
        for (int mf = 0; mf < 4; ++mf)
#pragma unroll
          for (int nf = 0; nf < 2; ++nf) {
            const int f = wc * 32 + nf * 16 + l15;
            const float sb = b5[f];
            const float hb = b5[128 + f];
#pragma unroll
            for (int reg = 0; reg < 4; ++reg) {
              const int rr = mf * 16 + l16 * 4 + reg;   // 0..63
              SP[rr * 132 + f] = accS[mf][nf][reg] + sb;
              HP[rr * 132 + f] = accH[mf][nf][reg] + hb;
            }
          }
      }
      __syncthreads();
#pragma unroll
      for (int it = 0; it < 4; ++it) {
        const int g = it * 512 + tid;          // 64 rows x 32 f4
        const int row = g >> 5, c4 = g & 31;
        const float4 s4 = *(const float4*)(SP + row * 132 + c4 * 4);
        const float4 h4 = *(const float4*)(HP + row * 132 + c4 * 4);
        const size_t nf4 = ((size_t)(n0 + mh * 64 + row)) * F_ + c4 * 4;
        for (int j = slot; j < NSLOT_; ++j) {
          if (!(fmask & (1u << j))) continue;
          const size_t idx = (size_t)j * ((size_t)N_ * F_) + nf4;
          const float4 x = *(const float4*)(x5 + idx);
          float4 y;
          y.x = x.x * s4.x + h4.x;
          y.y = x.y * s4.y + h4.y;
          y.z = x.z * s4.z + h4.z;
          y.w = x.w * s4.w + h4.w;
          *(float4*)(y5 + idx) = y;
        }
      }
      if (mh == 0) __syncthreads();
    }
    return;
  }

  // =========================== h6 duty ===========================
  const int ct = cz;
  const int col0 = ct * 256;

  for (int step = 0; step < K6_ / 64; ++step) {   // 18
    const int h = step >> 1;
    const int kk0 = (step & 1) << 6;
    const int k0 = step << 6;

    // stage A: gathered neighbor rows
#pragma unroll
    for (int q2 = 0; q2 < 2; ++q2) {
      const int q = w * 2 + q2;
      const int r = q * 8 + li8;
      const int lc = pc ^ (r & 7);
      const int m = ald[r * NH_ + h];
      const unsigned short* g = embB + embVarOff + (size_t)m * F_ + kk0 + lc * 8;
      load16(g, Asm + q * 1024);
    }
    // stage B: W6T rows col0..col0+255, K=1152
#pragma unroll
    for (int q2 = 0; q2 < 4; ++q2) {
      const int q = w * 4 + q2;
      const int j = q * 8 + li8;
      const int lc = pc ^ (j & 7);
      const unsigned short* g = W6T + (size_t)(col0 + j) * K6_ + k0 + lc * 8;
      load16(g, Bsm + q * 1024);
    }
    __syncthreads();

#pragma unroll
    for (int kf = 0; kf < 2; ++kf) {
      const int kc = kf * 4 + l16;
      bf16x8 a[4], bs[2], bh[2];
#pragma unroll
      for (int mf = 0; mf < 4; ++mf) {
        const int r = wr * 64 + mf * 16 + l15;
        a[mf] = *(const bf16x8*)(Asm + r * 128 + ((kc ^ (r & 7)) << 4));
      }
#pragma unroll
      for (int nf = 0; nf < 2; ++nf) {
        const int js = wc * 32 + nf * 16 + l15;
        bs[nf] = *(const bf16x8*)(Bsm + js * 128 + ((kc ^ (js & 7)) << 4));
        const int jh = js + 128;
        bh[nf] = *(const bf16x8*)(Bsm + jh * 128 + ((kc ^ (jh & 7)) << 4));
      }
#pragma unroll
      for (int mf = 0; mf < 4; ++mf)
#pragma unroll
        for (int nf = 0; nf < 2; ++nf) {
          accS[mf][nf] = __builtin_amdgcn_mfma_f32_16x16x32_bf16(a[mf], bs[nf], accS[mf][nf], 0, 0, 0);
          accH[mf][nf] = __builtin_amdgcn_mfma_f32_16x16x32_bf16(a[mf], bh[nf], accH[mf][nf], 0, 0, 0);
        }
    }
    __syncthreads();
  }

  // plane epilogue -> y6 (child-interleaved rows)
#pragma unroll 1
  for (int mh = 0; mh < 2; ++mh) {
    if (wr == mh) {
#pragma unroll
      for (int mf = 0; mf < 4; ++mf)
#pragma unroll
        for (int nf = 0; nf < 2; ++nf) {
          const int f = wc * 32 + nf * 16 + l15;
          const float sb = b6[col0 + f];
          const float hb = b6[col0 + 128 + f];
#pragma unroll
          for (int reg = 0; reg < 4; ++reg) {
            const int rr = mf * 16 + l16 * 4 + reg;   // 0..63
            SP[rr * 132 + f] = accS[mf][nf][reg] + sb;
            HP[rr * 132 + f] = accH[mf][nf][reg] + hb;
          }
        }
    }
    __syncthreads();
#pragma unroll
    for (int it = 0; it < 4; ++it) {
      const int g = it * 512 + tid;          // 64 rows x 32 f4
      const int row = g >> 5, c4 = g & 31;
      const float4 s4 = *(const float4*)(SP + row * 132 + c4 * 4);
      const float4 h4 = *(const float4*)(HP + row * 132 + c4 * 4);
      const size_t nupf = ((size_t)(4 * (n0 + mh * 64 + row) + ct)) * F_ + c4 * 4;
      for (int j = slot; j < NSLOT_; ++j) {
        if (!(fmask & (1u << j))) continue;
        const size_t idx = (size_t)j * ((size_t)NUP_ * F_) + nupf;
        const float4 x = *(const float4*)(x6 + idx);
        float4 y;
        y.x = x.x * s4.x + h4.x;
        y.y = x.y * s4.y + h4.y;
        y.z = x.z * s4.z + h4.z;
        y.w = x.w * s4.w + h4.w;
        *(float4*)(y6 + idx) = y;
      }
    }
    if (mh == 0) __syncthreads();            // planes rewritten next pass
  }
}

extern "C" void kernel_launch(void* const* d_in, const int* in_sizes, int n_in,
                              void* d_out, int out_size, void* d_ws, size_t ws_size,
                              hipStream_t stream) {
  (void)in_sizes; (void)n_in; (void)out_size; (void)ws_size;
  const float* emb = (const float*)d_in[0];
  const float* x5  = (const float*)d_in[1];
  const float* x6  = (const float*)d_in[2];
  const float* W5  = (const float*)d_in[3];
  const float* b5  = (const float*)d_in[4];
  const float* W6  = (const float*)d_in[5];
  const float* b6  = (const float*)d_in[6];
  const int* var_idx = (const int*)d_in[7];
  const int* adjc    = (const int*)d_in[8];

  float* y5 = (float*)d_out;
  float* y6 = y5 + (size_t)NSLOT_ * N_ * F_;

  unsigned short* embB = (unsigned short*)d_ws;                  // 12,582,912 bf16
  unsigned short* W5T  = embB + (size_t)NVARS_ * N_ * F_;        // 32,768 bf16
  unsigned short* W6T  = W5T + 256 * 128;                        // 1,179,648 bf16

  const int embN4 = NVARS_ * N_ * F_ / 4;
  k_conv_emb<<<(embN4 + 255) / 256, 256, 0, stream>>>((const float4*)emb, (ushort4*)embB, embN4);
  k_transpose_bf<<<dim3(256 / 32, 128 / 32), 256, 0, stream>>>(W5, W5T, 128, 256);
  k_transpose_bf<<<dim3(1024 / 32, 1152 / 32), 256, 0, stream>>>(W6, W6T, 1152, 1024);

  k_fused<<<dim3(N_ / 128, 5, NSLOT_), 512, 0, stream>>>(
      embB, W5T, W6T, b5, b6, x5, x6, var_idx, adjc, y5, y6);
}

// Round 10
// 332.013 us; speedup vs baseline: 1.0311x; 1.0311x over previous
//
#include <hip/hip_runtime.h>
#include <stdint.h>

// Problem constants
#define F_     128
#define N_     12288
#define NH_    9
#define NSLOT_ 8
#define NVARS_ 8
#define NUP_   (4*N_)
#define K6_    (NH_*F_)   // 1152

typedef __attribute__((ext_vector_type(8))) short bf16x8;
typedef __attribute__((ext_vector_type(4))) float f32x4;

typedef const __attribute__((address_space(1))) unsigned char* gp1_t;
typedef __attribute__((address_space(3))) unsigned char* lp3_t;

__device__ __forceinline__ void load16(const void* g, void* l) {
  __builtin_amdgcn_global_load_lds((gp1_t)g, (lp3_t)l, 16, 0, 0);
}

__device__ __forceinline__ unsigned short f2bf(float f) {
  union { float f; unsigned int u; } x; x.f = f;
  unsigned int u = x.u;
  unsigned int r = u + 0x7FFFu + ((u >> 16) & 1u);   // RNE
  return (unsigned short)(r >> 16);
}

// ---------------- converts ----------------
__global__ void k_conv_emb(const float4* __restrict__ src, ushort4* __restrict__ dst, int n4) {
  int i = blockIdx.x * blockDim.x + threadIdx.x;
  if (i >= n4) return;
  float4 v = src[i];
  ushort4 o;
  o.x = f2bf(v.x); o.y = f2bf(v.y); o.z = f2bf(v.z); o.w = f2bf(v.w);
  dst[i] = o;
}

// LDS-tiled coalesced transpose: dst[c][r] = bf16(src[r][c]); rows,cols multiples of 32.
__global__ __launch_bounds__(256) void k_transpose_bf(
    const float* __restrict__ src, unsigned short* __restrict__ dst, int rows, int cols) {
  __shared__ float tile[32][33];
  const int tx = threadIdx.x & 31, ty = threadIdx.x >> 5;   // 32 x 8
  const int c = blockIdx.x * 32 + tx;
#pragma unroll
  for (int i = 0; i < 4; ++i) {
    const int r = blockIdx.y * 32 + ty + i * 8;
    tile[ty + i * 8][tx] = src[(size_t)r * cols + c];
  }
  __syncthreads();
  const int rr = blockIdx.y * 32 + tx;                      // contiguous in dst row
#pragma unroll
  for (int i = 0; i < 4; ++i) {
    const int cc = blockIdx.x * 32 + ty + i * 8;            // dst row = src col
    dst[(size_t)cc * rows + rr] = f2bf(tile[tx][ty + i * 8]);
  }
}

// ---------------- zoom 5: var-dedup GEMM + plane epilogue (r8 version, unchanged) ------------
__global__ __launch_bounds__(256) void k_h5(
    const unsigned short* __restrict__ embB,   // [NVARS][N][F] bf16
    const unsigned short* __restrict__ W5T,    // [256][128]  bf16 (transposed W5)
    const float* __restrict__ b5,              // [256]
    const float* __restrict__ x5,              // [NSLOT][N][F]
    const int* __restrict__ var_idx,           // [NSLOT]
    const int* __restrict__ adjc,              // [N][9]
    float* __restrict__ y5)                    // [NSLOT][N][F]
{
  const int slot = blockIdx.y;
  const int var = var_idx[slot];
  for (int j = 0; j < NSLOT_; ++j) {
    if (j >= slot) break;
    if (var_idx[j] == var) return;            // uniform per block, before any barrier
  }
  unsigned int fmask = 0;
  for (int j = slot; j < NSLOT_; ++j)
    if (var_idx[j] == var) fmask |= 1u << j;

  __shared__ __align__(1024) unsigned char smem[8192 + 32768 + 64*4];
  unsigned char* Asm = smem;                 // 64 rows x 128 B (swizzled)
  unsigned char* Bsm = smem + 8192;          // 256 rows x 128 B (swizzled)
  int* ald = (int*)(smem + 8192 + 32768);

  const int tid = threadIdx.x;
  const int l = tid & 63, w = tid >> 6;
  const int wr = w >> 1, wc = w & 1;
  const int li8 = l >> 3, pc = l & 7, l15 = l & 15, l16 = l >> 4;

  const int nt = blockIdx.x;
  const int n0 = nt * 64;

  if (tid < 64) ald[tid] = adjc[(n0 + tid) * NH_];   // self index (col 0)
  __syncthreads();

  const f32x4 fz = {0.f, 0.f, 0.f, 0.f};
  f32x4 accS[2][4], accH[2][4];
#pragma unroll
  for (int mf = 0; mf < 2; ++mf)
#pragma unroll
    for (int nf = 0; nf < 4; ++nf) { accS[mf][nf] = fz; accH[mf][nf] = fz; }

  const size_t embVarOff = (size_t)var * ((size_t)N_ * F_);

  for (int step = 0; step < 2; ++step) {
    const int k0 = step << 6;
#pragma unroll
    for (int q2 = 0; q2 < 2; ++q2) {
      const int q = w * 2 + q2;
      const int r = q * 8 + li8;
      const int lc = pc ^ (r & 7);
      const unsigned short* g = embB + embVarOff + (size_t)ald[r] * F_ + k0 + lc * 8;
      load16(g, Asm + q * 1024);
    }
#pragma unroll
    for (int q2 = 0; q2 < 8; ++q2) {
      const int q = w * 8 + q2;
      const int j = q * 8 + li8;
      const int lc = pc ^ (j & 7);
      const unsigned short* g = W5T + (size_t)j * F_ + k0 + lc * 8;
      load16(g, Bsm + q * 1024);
    }
    __syncthreads();

#pragma unroll
    for (int kf = 0; kf < 2; ++kf) {
      const int kc = kf * 4 + l16;
      bf16x8 a[2], bs[4], bh[4];
#pragma unroll
      for (int mf = 0; mf < 2; ++mf) {
        const int r = wr * 32 + mf * 16 + l15;
        a[mf] = *(const bf16x8*)(Asm + r * 128 + ((kc ^ (r & 7)) << 4));
      }
#pragma unroll
      for (int nf = 0; nf < 4; ++nf) {
        const int js = wc * 64 + nf * 16 + l15;
        bs[nf] = *(const bf16x8*)(Bsm + js * 128 + ((kc ^ (js & 7)) << 4));
        const int jh = js + 128;
        bh[nf] = *(const bf16x8*)(Bsm + jh * 128 + ((kc ^ (jh & 7)) << 4));
      }
#pragma unroll
      for (int mf = 0; mf < 2; ++mf)
#pragma unroll
        for (int nf = 0; nf < 4; ++nf) {
          accS[mf][nf] = __builtin_amdgcn_mfma_f32_16x16x32_bf16(a[mf], bs[nf], accS[mf][nf], 0, 0, 0);
          accH[mf][nf] = __builtin_amdgcn_mfma_f32_16x16x32_bf16(a[mf], bh[nf], accH[mf][nf], 0, 0, 0);
        }
    }
    __syncthreads();
  }

  // ---- plane epilogue: scale/shift -> LDS [32][132] (padded), float4 streaming FiLM ----
  float* SP = (float*)smem;                  // [32][132]
  float* HP = SP + 32 * 132;                 // [32][132]
#pragma unroll 1
  for (int mh = 0; mh < 2; ++mh) {           // 32-row halves; owned by waves wr==mh
    if (wr == mh) {
#pragma unroll
      for (int mf = 0; mf < 2; ++mf)
#pragma unroll
        for (int nf = 0; nf < 4; ++nf) {
          const int f = wc * 64 + nf * 16 + l15;
          const float sb = b5[f];
          const float hb = b5[128 + f];
#pragma unroll
          for (int reg = 0; reg < 4; ++reg) {
            const int rr = mf * 16 + l16 * 4 + reg;   // 0..31
            SP[rr * 132 + f] = accS[mf][nf][reg] + sb;
            HP[rr * 132 + f] = accH[mf][nf][reg] + hb;
          }
        }
    }
    __syncthreads();
#pragma unroll
    for (int it = 0; it < 4; ++it) {
      const int g = it * 256 + tid;          // 32 rows x 32 f4
      const int row = g >> 5, c4 = g & 31;
      const float4 s4 = *(const float4*)(SP + row * 132 + c4 * 4);
      const float4 h4 = *(const float4*)(HP + row * 132 + c4 * 4);
      const size_t nf4 = ((size_t)(n0 + mh * 32 + row)) * F_ + c4 * 4;
      for (int j = slot; j < NSLOT_; ++j) {
        if (!(fmask & (1u << j))) continue;
        const size_t idx = (size_t)j * ((size_t)N_ * F_) + nf4;
        const float4 x = *(const float4*)(x5 + idx);
        float4 y;
        y.x = x.x * s4.x + h4.x;
        y.y = x.y * s4.y + h4.y;
        y.z = x.z * s4.z + h4.z;
        y.w = x.w * s4.w + h4.w;
        *(float4*)(y5 + idx) = y;
      }
    }
    if (mh == 0) __syncthreads();
  }
}

// ---------------- zoom 6: 128x(64S+64H) tile (m103-optimal 128^2 shape) + var-dedup ----------
// grid (96, 8, 8): y = ct*2+s -> child ct (0..3), col-strip s (0..1).
// Block computes rows n0..n0+127, scale cols cb..cb+63, shift cols cb+128..cb+191,
// cb = ct*256 + s*64. 256 thr = 4 waves (2 wr x 2 wc). 2-barrier K-loop, BK=64, 18 steps.
__global__ __launch_bounds__(256) void k_h6(
    const unsigned short* __restrict__ embB,   // [NVARS][N][F] bf16
    const unsigned short* __restrict__ W6T,    // [1024][1152] bf16 (transposed W6)
    const float* __restrict__ b6,              // [1024]
    const float* __restrict__ x6,              // [NSLOT][NUP][F]
    const int* __restrict__ var_idx,
    const int* __restrict__ adjc,              // [N][9]
    float* __restrict__ y6)                    // [NSLOT][NUP][F]
{
  const int slot = blockIdx.z;                // 0..7
  const int var = var_idx[slot];
  for (int j = 0; j < NSLOT_; ++j) {
    if (j >= slot) break;
    if (var_idx[j] == var) return;            // uniform per block, before any barrier
  }
  unsigned int fmask = 0;
  for (int j = slot; j < NSLOT_; ++j)
    if (var_idx[j] == var) fmask |= 1u << j;

  // union: GEMM (16K A + 16K B + 4.6K ald = 37.4K) vs epilogue planes (2 x 64 x 68 f32 = 34.8K)
  __shared__ __align__(1024) unsigned char smem[16384 + 16384 + 128*NH_*4];
  unsigned char* Asm = smem;                  // 128 rows x 128 B (swizzled)
  unsigned char* Bsm = smem + 16384;          // 128 rows x 128 B (swizzled): 64 S + 64 H
  int* ald = (int*)(smem + 32768);            // 128 x 9 neighbor ids

  const int tid = threadIdx.x;
  const int l = tid & 63, w = tid >> 6;       // 4 waves
  const int wr = w >> 1, wc = w & 1;          // 2 x 2
  const int li8 = l >> 3, pc = l & 7, l15 = l & 15, l16 = l >> 4;

  const int nt = blockIdx.x;                  // 0..95
  const int ct = blockIdx.y >> 1;             // child 0..3
  const int s  = blockIdx.y & 1;              // col strip 0..1
  const int n0 = nt * 128;
  const int cb = ct * 256 + s * 64;           // scale col base; shift at cb+128

  for (int t = tid; t < 128 * NH_; t += 256) ald[t] = adjc[n0 * NH_ + t];
  __syncthreads();

  const f32x4 fz = {0.f, 0.f, 0.f, 0.f};
  f32x4 accS[4][2], accH[4][2];
#pragma unroll
  for (int mf = 0; mf < 4; ++mf)
#pragma unroll
    for (int nf = 0; nf < 2; ++nf) { accS[mf][nf] = fz; accH[mf][nf] = fz; }

  const size_t embVarOff = (size_t)var * ((size_t)N_ * F_);

  for (int step = 0; step < K6_ / 64; ++step) {   // 18
    const int h = step >> 1;
    const int kk0 = (step & 1) << 6;              // offset within emb row (F=128)
    const int k0 = step << 6;                     // offset within W6T row (K=1152)

    // stage A: 16 chunks, 4 per wave (gathered rows)
#pragma unroll
    for (int q2 = 0; q2 < 4; ++q2) {
      const int q = w * 4 + q2;
      const int r = q * 8 + li8;                  // 0..127
      const int lc = pc ^ (r & 7);
      const int m = ald[r * NH_ + h];
      const unsigned short* g = embB + embVarOff + (size_t)m * F_ + kk0 + lc * 8;
      load16(g, Asm + q * 1024);
    }
    // stage B: 16 chunks, 4 per wave; LDS row j: 0..63 -> W6T row cb+j (S), 64..127 -> cb+128+(j-64) (H)
#pragma unroll
    for (int q2 = 0; q2 < 4; ++q2) {
      const int q = w * 4 + q2;
      const int j = q * 8 + li8;                  // 0..127
      const int lc = pc ^ (j & 7);
      const int wrow = cb + (j & 63) + ((j >> 6) << 7);
      const unsigned short* g = W6T + (size_t)wrow * K6_ + k0 + lc * 8;
      load16(g, Bsm + q * 1024);
    }
    __syncthreads();

#pragma unroll
    for (int kf = 0; kf < 2; ++kf) {
      const int kc = kf * 4 + l16;
      bf16x8 a[4], bs[2], bh[2];
#pragma unroll
      for (int mf = 0; mf < 4; ++mf) {
        const int r = wr * 64 + mf * 16 + l15;
        a[mf] = *(const bf16x8*)(Asm + r * 128 + ((kc ^ (r & 7)) << 4));
      }
#pragma unroll
      for (int nf = 0; nf < 2; ++nf) {
        const int js = wc * 32 + nf * 16 + l15;         // 0..63 (S rows)
        bs[nf] = *(const bf16x8*)(Bsm + js * 128 + ((kc ^ (js & 7)) << 4));
        const int jh = js + 64;                         // 64..127 (H rows)
        bh[nf] = *(const bf16x8*)(Bsm + jh * 128 + ((kc ^ (jh & 7)) << 4));
      }
#pragma unroll
      for (int mf = 0; mf < 4; ++mf)
#pragma unroll
        for (int nf = 0; nf < 2; ++nf) {
          accS[mf][nf] = __builtin_amdgcn_mfma_f32_16x16x32_bf16(a[mf], bs[nf], accS[mf][nf], 0, 0, 0);
          accH[mf][nf] = __builtin_amdgcn_mfma_f32_16x16x32_bf16(a[mf], bh[nf], accH[mf][nf], 0, 0, 0);
        }
    }
    __syncthreads();
  }

  // ---- plane epilogue: scale/shift -> LDS [64][68] (padded), float4 streaming FiLM ----
  float* SP = (float*)smem;                  // [64][68]
  float* HP = SP + 64 * 68;                  // [64][68]
#pragma unroll 1
  for (int mh = 0; mh < 2; ++mh) {           // 64-row halves; owned by waves wr==mh
    if (wr == mh) {
#pragma unroll
      for (int mf = 0; mf < 4; ++mf)
#pragma unroll
        for (int nf = 0; nf < 2; ++nf) {
          const int f = wc * 32 + nf * 16 + l15;        // 0..63
          const float sb = b6[cb + f];
          const float hb = b6[cb + 128 + f];
#pragma unroll
          for (int reg = 0; reg < 4; ++reg) {
            const int rr = mf * 16 + l16 * 4 + reg;     // 0..63
            SP[rr * 68 + f] = accS[mf][nf][reg] + sb;
            HP[rr * 68 + f] = accH[mf][nf][reg] + hb;
          }
        }
    }
    __syncthreads();
#pragma unroll
    for (int it = 0; it < 4; ++it) {
      const int g = it * 256 + tid;          // 64 rows x 16 f4
      const int row = g >> 4, c4 = g & 15;
      const float4 s4 = *(const float4*)(SP + row * 68 + c4 * 4);
      const float4 h4 = *(const float4*)(HP + row * 68 + c4 * 4);
      const size_t nupf = ((size_t)(4 * (n0 + mh * 64 + row) + ct)) * F_ + cb - ct * 256 + c4 * 4;
      for (int j = slot; j < NSLOT_; ++j) {
        if (!(fmask & (1u << j))) continue;
        const size_t idx = (size_t)j * ((size_t)NUP_ * F_) + nupf;
        const float4 x = *(const float4*)(x6 + idx);
        float4 y;
        y.x = x.x * s4.x + h4.x;
        y.y = x.y * s4.y + h4.y;
        y.z = x.z * s4.z + h4.z;
        y.w = x.w * s4.w + h4.w;
        *(float4*)(y6 + idx) = y;
      }
    }
    if (mh == 0) __syncthreads();            // planes rewritten next pass
  }
}

extern "C" void kernel_launch(void* const* d_in, const int* in_sizes, int n_in,
                              void* d_out, int out_size, void* d_ws, size_t ws_size,
                              hipStream_t stream) {
  (void)in_sizes; (void)n_in; (void)out_size; (void)ws_size;
  const float* emb = (const float*)d_in[0];
  const float* x5  = (const float*)d_in[1];
  const float* x6  = (const float*)d_in[2];
  const float* W5  = (const float*)d_in[3];
  const float* b5  = (const float*)d_in[4];
  const float* W6  = (const float*)d_in[5];
  const float* b6  = (const float*)d_in[6];
  const int* var_idx = (const int*)d_in[7];
  const int* adjc    = (const int*)d_in[8];

  float* y5 = (float*)d_out;
  float* y6 = y5 + (size_t)NSLOT_ * N_ * F_;

  unsigned short* embB = (unsigned short*)d_ws;                  // 12,582,912 bf16
  unsigned short* W5T  = embB + (size_t)NVARS_ * N_ * F_;        // 32,768 bf16
  unsigned short* W6T  = W5T + 256 * 128;                        // 1,179,648 bf16

  const int embN4 = NVARS_ * N_ * F_ / 4;
  k_conv_emb<<<(embN4 + 255) / 256, 256, 0, stream>>>((const float4*)emb, (ushort4*)embB, embN4);
  k_transpose_bf<<<dim3(256 / 32, 128 / 32), 256, 0, stream>>>(W5, W5T, 128, 256);
  k_transpose_bf<<<dim3(1024 / 32, 1152 / 32), 256, 0, stream>>>(W6, W6T, 1152, 1024);

  k_h6<<<dim3(N_ / 128, 8, NSLOT_), 256, 0, stream>>>(embB, W6T, b6, x6, var_idx, adjc, y6);
  k_h5<<<dim3(N_ / 64, NSLOT_), 256, 0, stream>>>(embB, W5T, b5, x5, var_idx, adjc, y5);
}

// Round 12
// 261.278 us; speedup vs baseline: 1.3102x; 1.2707x over previous
//
#include <hip/hip_runtime.h>
#include <stdint.h>

// Problem constants
#define F_     128
#define N_     12288
#define NH_    9
#define NSLOT_ 8
#define NVARS_ 8
#define NUP_   (4*N_)
#define K6_    (NH_*F_)   // 1152

typedef __attribute__((ext_vector_type(8))) short bf16x8;
typedef __attribute__((ext_vector_type(4))) float f32x4;

typedef const __attribute__((address_space(1))) unsigned char* gp1_t;
typedef __attribute__((address_space(3))) unsigned char* lp3_t;

__device__ __forceinline__ void load16(const void* g, void* l) {
  __builtin_amdgcn_global_load_lds((gp1_t)g, (lp3_t)l, 16, 0, 0);
}

__device__ __forceinline__ unsigned short f2bf(float f) {
  union { float f; unsigned int u; } x; x.f = f;
  unsigned int u = x.u;
  unsigned int r = u + 0x7FFFu + ((u >> 16) & 1u);   // RNE
  return (unsigned short)(r >> 16);
}

// ---------------- converts ----------------
__global__ void k_conv_emb(const float4* __restrict__ src, ushort4* __restrict__ dst, int n4) {
  int i = blockIdx.x * blockDim.x + threadIdx.x;
  if (i >= n4) return;
  float4 v = src[i];
  ushort4 o;
  o.x = f2bf(v.x); o.y = f2bf(v.y); o.z = f2bf(v.z); o.w = f2bf(v.w);
  dst[i] = o;
}

// LDS-tiled coalesced transpose: dst[c][r] = bf16(src[r][c]); rows,cols multiples of 32.
__global__ __launch_bounds__(256) void k_transpose_bf(
    const float* __restrict__ src, unsigned short* __restrict__ dst, int rows, int cols) {
  __shared__ float tile[32][33];
  const int tx = threadIdx.x & 31, ty = threadIdx.x >> 5;   // 32 x 8
  const int c = blockIdx.x * 32 + tx;
#pragma unroll
  for (int i = 0; i < 4; ++i) {
    const int r = blockIdx.y * 32 + ty + i * 8;
    tile[ty + i * 8][tx] = src[(size_t)r * cols + c];
  }
  __syncthreads();
  const int rr = blockIdx.y * 32 + tx;                      // contiguous in dst row
#pragma unroll
  for (int i = 0; i < 4; ++i) {
    const int cc = blockIdx.x * 32 + ty + i * 8;            // dst row = src col
    dst[(size_t)cc * rows + rr] = f2bf(tile[tx][ty + i * 8]);
  }
}

// ---------------- zoom 5: var-dedup GEMM + plane epilogue (r8 version) ----------------
// block: 64 rows x 256 cols, 256 thr (4 waves: 2 wr x 2 wc), BK=64, 2 k-steps
__global__ __launch_bounds__(256) void k_h5(
    const unsigned short* __restrict__ embB,   // [NVARS][N][F] bf16
    const unsigned short* __restrict__ W5T,    // [256][128]  bf16 (transposed W5)
    const float* __restrict__ b5,              // [256]
    const float* __restrict__ x5,              // [NSLOT][N][F]
    const int* __restrict__ var_idx,           // [NSLOT]
    const int* __restrict__ adjc,              // [N][9]
    float* __restrict__ y5)                    // [NSLOT][N][F]
{
  const int slot = blockIdx.y;
  const int var = var_idx[slot];
  for (int j = 0; j < NSLOT_; ++j) {
    if (j >= slot) break;
    if (var_idx[j] == var) return;            // uniform per block, before any barrier
  }
  unsigned int fmask = 0;
  for (int j = slot; j < NSLOT_; ++j)
    if (var_idx[j] == var) fmask |= 1u << j;

  __shared__ __align__(1024) unsigned char smem[8192 + 32768 + 64*4];
  unsigned char* Asm = smem;                 // 64 rows x 128 B (swizzled)
  unsigned char* Bsm = smem + 8192;          // 256 rows x 128 B (swizzled)
  int* ald = (int*)(smem + 8192 + 32768);

  const int tid = threadIdx.x;
  const int l = tid & 63, w = tid >> 6;
  const int wr = w >> 1, wc = w & 1;
  const int li8 = l >> 3, pc = l & 7, l15 = l & 15, l16 = l >> 4;

  const int nt = blockIdx.x;
  const int n0 = nt * 64;

  if (tid < 64) ald[tid] = adjc[(n0 + tid) * NH_];   // self index (col 0)
  __syncthreads();

  const f32x4 fz = {0.f, 0.f, 0.f, 0.f};
  f32x4 accS[2][4], accH[2][4];
#pragma unroll
  for (int mf = 0; mf < 2; ++mf)
#pragma unroll
    for (int nf = 0; nf < 4; ++nf) { accS[mf][nf] = fz; accH[mf][nf] = fz; }

  const size_t embVarOff = (size_t)var * ((size_t)N_ * F_);

  for (int step = 0; step < 2; ++step) {
    const int k0 = step << 6;
#pragma unroll
    for (int q2 = 0; q2 < 2; ++q2) {
      const int q = w * 2 + q2;
      const int r = q * 8 + li8;
      const int lc = pc ^ (r & 7);
      const unsigned short* g = embB + embVarOff + (size_t)ald[r] * F_ + k0 + lc * 8;
      load16(g, Asm + q * 1024);
    }
#pragma unroll
    for (int q2 = 0; q2 < 8; ++q2) {
      const int q = w * 8 + q2;
      const int j = q * 8 + li8;
      const int lc = pc ^ (j & 7);
      const unsigned short* g = W5T + (size_t)j * F_ + k0 + lc * 8;
      load16(g, Bsm + q * 1024);
    }
    __syncthreads();

#pragma unroll
    for (int kf = 0; kf < 2; ++kf) {
      const int kc = kf * 4 + l16;
      bf16x8 a[2], bs[4], bh[4];
#pragma unroll
      for (int mf = 0; mf < 2; ++mf) {
        const int r = wr * 32 + mf * 16 + l15;
        a[mf] = *(const bf16x8*)(Asm + r * 128 + ((kc ^ (r & 7)) << 4));
      }
#pragma unroll
      for (int nf = 0; nf < 4; ++nf) {
        const int js = wc * 64 + nf * 16 + l15;
        bs[nf] = *(const bf16x8*)(Bsm + js * 128 + ((kc ^ (js & 7)) << 4));
        const int jh = js + 128;
        bh[nf] = *(const bf16x8*)(Bsm + jh * 128 + ((kc ^ (jh & 7)) << 4));
      }
#pragma unroll
      for (int mf = 0; mf < 2; ++mf)
#pragma unroll
        for (int nf = 0; nf < 4; ++nf) {
          accS[mf][nf] = __builtin_amdgcn_mfma_f32_16x16x32_bf16(a[mf], bs[nf], accS[mf][nf], 0, 0, 0);
          accH[mf][nf] = __builtin_amdgcn_mfma_f32_16x16x32_bf16(a[mf], bh[nf], accH[mf][nf], 0, 0, 0);
        }
    }
    __syncthreads();
  }

  // ---- plane epilogue: scale/shift -> LDS [32][132] (padded), float4 streaming FiLM ----
  float* SP = (float*)smem;                  // [32][132]
  float* HP = SP + 32 * 132;                 // [32][132]
#pragma unroll 1
  for (int mh = 0; mh < 2; ++mh) {           // 32-row halves; owned by waves wr==mh
    if (wr == mh) {
#pragma unroll
      for (int mf = 0; mf < 2; ++mf)
#pragma unroll
        for (int nf = 0; nf < 4; ++nf) {
          const int f = wc * 64 + nf * 16 + l15;
          const float sb = b5[f];
          const float hb = b5[128 + f];
#pragma unroll
          for (int reg = 0; reg < 4; ++reg) {
            const int rr = mf * 16 + l16 * 4 + reg;   // 0..31
            SP[rr * 132 + f] = accS[mf][nf][reg] + sb;
            HP[rr * 132 + f] = accH[mf][nf][reg] + hb;
          }
        }
    }
    __syncthreads();
#pragma unroll
    for (int it = 0; it < 4; ++it) {
      const int g = it * 256 + tid;          // 32 rows x 32 f4
      const int row = g >> 5, c4 = g & 31;
      const float4 s4 = *(const float4*)(SP + row * 132 + c4 * 4);
      const float4 h4 = *(const float4*)(HP + row * 132 + c4 * 4);
      const size_t nf4 = ((size_t)(n0 + mh * 32 + row)) * F_ + c4 * 4;
      for (int j = slot; j < NSLOT_; ++j) {
        if (!(fmask & (1u << j))) continue;
        const size_t idx = (size_t)j * ((size_t)N_ * F_) + nf4;
        const float4 x = *(const float4*)(x5 + idx);
        float4 y;
        y.x = x.x * s4.x + h4.x;
        y.y = x.y * s4.y + h4.y;
        y.z = x.z * s4.z + h4.z;
        y.w = x.w * s4.w + h4.w;
        *(float4*)(y5 + idx) = y;
      }
    }
    if (mh == 0) __syncthreads();
  }
}

// ---------------- zoom 6: r8 2-barrier GEMM + var-dedup + plane epilogue ----------------
// block: 128 rows x 256 cols (one child ct), 512 thr (8 waves: 2 wr x 4 wc), BK=64, 18 steps
__global__ __launch_bounds__(512) void k_h6(
    const unsigned short* __restrict__ embB,   // [NVARS][N][F] bf16
    const unsigned short* __restrict__ W6T,    // [1024][1152] bf16 (transposed W6)
    const float* __restrict__ b6,              // [1024]
    const float* __restrict__ x6,              // [NSLOT][NUP][F]
    const int* __restrict__ var_idx,
    const int* __restrict__ adjc,              // [N][9]
    float* __restrict__ y6)                    // [NSLOT][NUP][F]
{
  const int slot = blockIdx.z;                // 0..7
  const int var = var_idx[slot];
  for (int j = 0; j < NSLOT_; ++j) {
    if (j >= slot) break;
    if (var_idx[j] == var) return;            // uniform per block, before any barrier
  }
  unsigned int fmask = 0;
  for (int j = slot; j < NSLOT_; ++j)
    if (var_idx[j] == var) fmask |= 1u << j;

  // union: GEMM layout (16K A + 32K B + 4.6K ald = 53.8K) vs epilogue planes (2x33.8K = 67.6K)
  __shared__ __align__(1024) unsigned char smem[2 * 64 * 132 * 4];
  unsigned char* Asm = smem;                  // 128 rows x 128 B (swizzled)
  unsigned char* Bsm = smem + 16384;          // 256 rows x 128 B (swizzled)
  int* ald = (int*)(smem + 16384 + 32768);    // 128 x 9 neighbor ids

  const int tid = threadIdx.x;
  const int l = tid & 63, w = tid >> 6;       // 8 waves
  const int wr = w >> 2, wc = w & 3;          // 2 x 4
  const int li8 = l >> 3, pc = l & 7, l15 = l & 15, l16 = l >> 4;

  const int nt = blockIdx.x;                  // 0..95
  const int ct = blockIdx.y;                  // child 0..3
  const int n0 = nt * 128;
  const int col0 = ct * 256;

  for (int t = tid; t < 128 * NH_; t += 512) ald[t] = adjc[n0 * NH_ + t];
  __syncthreads();

  const f32x4 fz = {0.f, 0.f, 0.f, 0.f};
  f32x4 accS[4][2], accH[4][2];
#pragma unroll
  for (int mf = 0; mf < 4; ++mf)
#pragma unroll
    for (int nf = 0; nf < 2; ++nf) { accS[mf][nf] = fz; accH[mf][nf] = fz; }

  const size_t embVarOff = (size_t)var * ((size_t)N_ * F_);

  for (int step = 0; step < K6_ / 64; ++step) {   // 18
    const int h = step >> 1;
    const int kk0 = (step & 1) << 6;              // offset within emb row (F=128)
    const int k0 = step << 6;                     // offset within W6T row (K=1152)

    // stage A: 16 chunks, 2 per wave (gathered rows)
#pragma unroll
    for (int q2 = 0; q2 < 2; ++q2) {
      const int q = w * 2 + q2;
      const int r = q * 8 + li8;                  // 0..127
      const int lc = pc ^ (r & 7);
      const int m = ald[r * NH_ + h];
      const unsigned short* g = embB + embVarOff + (size_t)m * F_ + kk0 + lc * 8;
      load16(g, Asm + q * 1024);
    }
    // stage B: 32 chunks, 4 per wave
#pragma unroll
    for (int q2 = 0; q2 < 4; ++q2) {
      const int q = w * 4 + q2;
      const int j = q * 8 + li8;                  // 0..255
      const int lc = pc ^ (j & 7);
      const unsigned short* g = W6T + (size_t)(col0 + j) * K6_ + k0 + lc * 8;
      load16(g, Bsm + q * 1024);
    }
    __syncthreads();

#pragma unroll
    for (int kf = 0; kf < 2; ++kf) {
      const int kc = kf * 4 + l16;
      bf16x8 a[4], bs[2], bh[2];
#pragma unroll
      for (int mf = 0; mf < 4; ++mf) {
        const int r = wr * 64 + mf * 16 + l15;
        a[mf] = *(const bf16x8*)(Asm + r * 128 + ((kc ^ (r & 7)) << 4));
      }
#pragma unroll
      for (int nf = 0; nf < 2; ++nf) {
        const int js = wc * 32 + nf * 16 + l15;
        bs[nf] = *(const bf16x8*)(Bsm + js * 128 + ((kc ^ (js & 7)) << 4));
        const int jh = js + 128;
        bh[nf] = *(const bf16x8*)(Bsm + jh * 128 + ((kc ^ (jh & 7)) << 4));
      }
#pragma unroll
      for (int mf = 0; mf < 4; ++mf)
#pragma unroll
        for (int nf = 0; nf < 2; ++nf) {
          accS[mf][nf] = __builtin_amdgcn_mfma_f32_16x16x32_bf16(a[mf], bs[nf], accS[mf][nf], 0, 0, 0);
          accH[mf][nf] = __builtin_amdgcn_mfma_f32_16x16x32_bf16(a[mf], bh[nf], accH[mf][nf], 0, 0, 0);
        }
    }
    __syncthreads();
  }

  // ---- plane epilogue: scale/shift -> LDS [64][132] (padded), float4 streaming FiLM ----
  // Wave (wr,wc) owns rows wr*64..+63, S-cols wc*32..+31 (H at +128). Padding 132 makes the
  // scalar plane write 2-way-conflict max (free, m136); reads/stores are float4 coalesced.
  float* SP = (float*)smem;                  // [64][132]
  float* HP = SP + 64 * 132;                 // [64][132]
#pragma unroll 1
  for (int mh = 0; mh < 2; ++mh) {           // 64-row halves; owned by waves wr==mh
    if (wr == mh) {
#pragma unroll
      for (int mf = 0; mf < 4; ++mf)
#pragma unroll
        for (int nf = 0; nf < 2; ++nf) {
          const int f = wc * 32 + nf * 16 + l15;
          const float sb = b6[col0 + f];
          const float hb = b6[col0 + 128 + f];
#pragma unroll
          for (int reg = 0; reg < 4; ++reg) {
            const int rr = mf * 16 + l16 * 4 + reg;   // 0..63
            SP[rr * 132 + f] = accS[mf][nf][reg] + sb;
            HP[rr * 132 + f] = accH[mf][nf][reg] + hb;
          }
        }
    }
    __syncthreads();
#pragma unroll
    for (int it = 0; it < 4; ++it) {
      const int g = it * 512 + tid;          // 64 rows x 32 f4
      const int row = g >> 5, c4 = g & 31;
      const float4 s4 = *(const float4*)(SP + row * 132 + c4 * 4);
      const float4 h4 = *(const float4*)(HP + row * 132 + c4 * 4);
      const size_t nupf = ((size_t)(4 * (n0 + mh * 64 + row) + ct)) * F_ + c4 * 4;
      for (int j = slot; j < NSLOT_; ++j) {
        if (!(fmask & (1u << j))) continue;
        const size_t idx = (size_t)j * ((size_t)NUP_ * F_) + nupf;
        const float4 x = *(const float4*)(x6 + idx);
        float4 y;
        y.x = x.x * s4.x + h4.x;
        y.y = x.y * s4.y + h4.y;
        y.z = x.z * s4.z + h4.z;
        y.w = x.w * s4.w + h4.w;
        *(float4*)(y6 + idx) = y;
      }
    }
    if (mh == 0) __syncthreads();            // planes rewritten next pass
  }
}

extern "C" void kernel_launch(void* const* d_in, const int* in_sizes, int n_in,
                              void* d_out, int out_size, void* d_ws, size_t ws_size,
                              hipStream_t stream) {
  (void)in_sizes; (void)n_in; (void)out_size; (void)ws_size;
  const float* emb = (const float*)d_in[0];
  const float* x5  = (const float*)d_in[1];
  const float* x6  = (const float*)d_in[2];
  const float* W5  = (const float*)d_in[3];
  const float* b5  = (const float*)d_in[4];
  const float* W6  = (const float*)d_in[5];
  const float* b6  = (const float*)d_in[6];
  const int* var_idx = (const int*)d_in[7];
  const int* adjc    = (const int*)d_in[8];

  float* y5 = (float*)d_out;
  float* y6 = y5 + (size_t)NSLOT_ * N_ * F_;

  unsigned short* embB = (unsigned short*)d_ws;                  // 12,582,912 bf16
  unsigned short* W5T  = embB + (size_t)NVARS_ * N_ * F_;        // 32,768 bf16
  unsigned short* W6T  = W5T + 256 * 128;                        // 1,179,648 bf16

  const int embN4 = NVARS_ * N_ * F_ / 4;
  k_conv_emb<<<(embN4 + 255) / 256, 256, 0, stream>>>((const float4*)emb, (ushort4*)embB, embN4);
  k_transpose_bf<<<dim3(256 / 32, 128 / 32), 256, 0, stream>>>(W5, W5T, 128, 256);
  k_transpose_bf<<<dim3(1024 / 32, 1152 / 32), 256, 0, stream>>>(W6, W6T, 1152, 1024);

  k_h6<<<dim3(N_ / 128, 4, NSLOT_), 512, 0, stream>>>(embB, W6T, b6, x6, var_idx, adjc, y6);
  k_h5<<<dim3(N_ / 64, NSLOT_), 256, 0, stream>>>(embB, W5T, b5, x5, var_idx, adjc, y5);
}